// Round 7
// baseline (226.775 us; speedup 1.0000x reference)
//
#include <hip/hip_runtime.h>

#define DD 128

typedef __attribute__((ext_vector_type(8))) short short8;
typedef __attribute__((ext_vector_type(4))) float float4v;

static __device__ __forceinline__ unsigned short f2bf(float x) {
    unsigned u = __builtin_bit_cast(unsigned, x);
    u += 0x7fffu + ((u >> 16) & 1u);   // RNE
    return (unsigned short)(u >> 16);
}
static __device__ __forceinline__ float bflo(unsigned u) {
    return __builtin_bit_cast(float, u << 16);
}
static __device__ __forceinline__ float bfhi(unsigned u) {
    return __builtin_bit_cast(float, u & 0xffff0000u);
}

// ---- fused init: [0,128) emb@W1 -> bf16 table; [128,136) W2 swizzle; [136,..) zero cnt ----
__global__ __launch_bounds__(256) void k_init(const float* __restrict__ emb,
                                              const float* __restrict__ W1,
                                              const float* __restrict__ W2,
                                              unsigned* __restrict__ embW1b,
                                              unsigned short* __restrict__ Wb,
                                              int* __restrict__ cnt, int N) {
    int blk = blockIdx.x;
    if (blk < 128) {
        // embW1b: 4 rows per block, one wave per row
        int w = threadIdx.x >> 6;
        int t = threadIdx.x & 63;
        int p = blk * 4 + w;
        int c0 = t * 2, c1 = t * 2 + 1;
        float s0 = 0.f, s1 = 0.f;
#pragma unroll 8
        for (int k = 0; k < DD; k++) {
            float e = emb[p * DD + k];
            s0 += e * W1[k * DD + c0];
            s1 += e * W1[k * DD + c1];
        }
        embW1b[p * 64 + t] = (unsigned)f2bf(s0) | ((unsigned)f2bf(s1) << 16);
    } else if (blk < 136) {
        int t = (blk - 128) * 256 + threadIdx.x;   // 0..2047: (nt, ks, lane)
        int nt = t >> 8, ks = (t >> 6) & 3, lane = t & 63;
        int n = nt * 16 + (lane & 15);
        int kbase = ks * 32 + (lane >> 4) * 8;
        unsigned short* o = Wb + (size_t)t * 8;
#pragma unroll
        for (int j = 0; j < 8; j++)
            o[j] = f2bf(W2[(kbase + j) * DD + n]);
    } else {
        int base = (blk - 136) * 1024 + threadIdx.x * 4;
        if (base + 3 < N) {
            *(int4*)(cnt + base) = make_int4(0, 0, 0, 0);
        } else {
            if (base + 0 < N) cnt[base + 0] = 0;
            if (base + 1 < N) cnt[base + 1] = 0;
            if (base + 2 < N) cnt[base + 2] = 0;
            if (base + 3 < N) cnt[base + 3] = 0;
        }
    }
}

// ---- in-degree histogram (int) ----
__global__ void k_hist(const int* __restrict__ dst, int* __restrict__ cnt, int E) {
    int e = blockIdx.x * blockDim.x + threadIdx.x;
    if (e < E) atomicAdd(&cnt[dst[e]], 1);
}

// ---- scan phase 1: per-1024-tile exclusive prefix + block totals + dis ----
__global__ __launch_bounds__(256) void k_scan1(const int* __restrict__ cnt,
                                               int* __restrict__ rowptr,
                                               float* __restrict__ dis,
                                               int* __restrict__ bsum, int N) {
    __shared__ int sums[256];
    int t = threadIdx.x;
    int base = blockIdx.x * 1024 + t * 4;
    int c0 = 0, c1 = 0, c2 = 0, c3 = 0;
    if (base + 3 < N) {
        const int4 v = *(const int4*)(cnt + base);
        c0 = v.x; c1 = v.y; c2 = v.z; c3 = v.w;
    } else {
        if (base + 0 < N) c0 = cnt[base + 0];
        if (base + 1 < N) c1 = cnt[base + 1];
        if (base + 2 < N) c2 = cnt[base + 2];
        if (base + 3 < N) c3 = cnt[base + 3];
    }
    int ts = c0 + c1 + c2 + c3;
    sums[t] = ts;
    __syncthreads();
    for (int off = 1; off < 256; off <<= 1) {
        int v = (t >= off) ? sums[t - off] : 0;
        __syncthreads();
        sums[t] += v;
        __syncthreads();
    }
    int pre = sums[t] - ts;
    if (base + 0 < N) { rowptr[base + 0] = pre;                 dis[base + 0] = rsqrtf((float)c0 + 1.f); }
    if (base + 1 < N) { rowptr[base + 1] = pre + c0;            dis[base + 1] = rsqrtf((float)c1 + 1.f); }
    if (base + 2 < N) { rowptr[base + 2] = pre + c0 + c1;       dis[base + 2] = rsqrtf((float)c2 + 1.f); }
    if (base + 3 < N) { rowptr[base + 3] = pre + c0 + c1 + c2;  dis[base + 3] = rsqrtf((float)c3 + 1.f); }
    if (t == 255) bsum[blockIdx.x] = sums[255];
}

// ---- scan phase 2+3 fused: each block redundantly prefixes bsum (B<=256), applies offsets ----
__global__ __launch_bounds__(256) void k_scan23(int* __restrict__ rowptr,
                                                int* __restrict__ cursor,
                                                const int* __restrict__ bsum,
                                                int B, int N, int E) {
    __shared__ int pref[256];
    int t = threadIdx.x;
    pref[t] = (t < B) ? bsum[t] : 0;
    __syncthreads();
    int i = blockIdx.x * 256 + t;
    if (i < N) {
        int b = i >> 10;
        int off = 0;
        for (int k = 0; k < b; k++) off += pref[k];   // <=48 LDS broadcasts
        int v = rowptr[i] + off;
        rowptr[i] = v;
        cursor[i] = v;
    }
    if (i == 0) rowptr[N] = E;
}

// ---- bucket edges by dst: single per-edge stream srcs ----
__global__ void k_bucket(const int* __restrict__ src, const int* __restrict__ dst,
                         int* __restrict__ cursor, int* __restrict__ srcs, int E) {
    int e = blockIdx.x * blockDim.x + threadIdx.x;
    if (e >= E) return;
    int s = src[e], d = dst[e];
    int pos = atomicAdd(&cursor[d], 1);
    srcs[pos] = s;
}

// ---- fused layer1 + strip GEMM: 1024-thread block = 16 nodes (one wave each) + MFMA strip ----
__global__ __launch_bounds__(1024) void k_node1g(const int* __restrict__ rowptr,
                                                 const int* __restrict__ srcs,
                                                 const int* __restrict__ node_ids,
                                                 const float* __restrict__ emb,
                                                 const unsigned* __restrict__ embW1b,
                                                 const float* __restrict__ dis,
                                                 const float* __restrict__ b1,
                                                 const float* __restrict__ g1,
                                                 const float* __restrict__ beta1,
                                                 unsigned* __restrict__ x1b,
                                                 const unsigned short* __restrict__ Wb,
                                                 unsigned short* __restrict__ hb, int N) {
    __shared__ unsigned xs[16 * 68];   // stride 68 (272B): breaks bank alignment for strip reads
    int wid = threadIdx.x >> 6;        // 0..15
    int lane = threadIdx.x & 63;
    int row0 = blockIdx.x * 16;
    int i = row0 + wid;

    if (i < N) {
        int r0 = rowptr[i], r1 = rowptr[i + 1];
        int c = lane * 2;
        float ax = 0.f, ay = 0.f;
        int j = r0;
        for (; j + 7 < r1; j += 8) {
            float axp = 0.f, ayp = 0.f;
#pragma unroll
            for (int q = 0; q < 8; q++) {
                int s = srcs[j + q];
                float n = dis[s];
                unsigned a = embW1b[node_ids[s] * 64 + lane];
                axp += bflo(a) * n; ayp += bfhi(a) * n;
            }
            ax += axp; ay += ayp;
        }
        for (; j < r1; j++) {
            int s = srcs[j];
            float n = dis[s];
            unsigned a = embW1b[node_ids[s] * 64 + lane];
            ax += bflo(a) * n; ay += bfhi(a) * n;
        }
        float di = dis[i];
        int pid = node_ids[i];
        float2 ev = *(const float2*)(emb + (size_t)pid * DD + c);
        unsigned hw = embW1b[pid * 64 + lane];
        float v0 = ev.x + di * (ax + di * bflo(hw)) + b1[c];
        float v1 = ev.y + di * (ay + di * bfhi(hw)) + b1[c + 1];
        float sum = v0 + v1;
#pragma unroll
        for (int o = 32; o >= 1; o >>= 1) sum += __shfl_xor(sum, o, 64);
        float mu = sum * (1.f / DD);
        float d0 = v0 - mu, d1 = v1 - mu;
        float ss = d0 * d0 + d1 * d1;
#pragma unroll
        for (int o = 32; o >= 1; o >>= 1) ss += __shfl_xor(ss, o, 64);
        float r = rsqrtf(ss * (1.f / DD) + 1e-5f);
        float o0 = d0 * r * g1[c] + beta1[c];
        float o1 = d1 * r * g1[c + 1] + beta1[c + 1];
        unsigned packed = (unsigned)f2bf(o0) | ((unsigned)f2bf(o1) << 16);
        x1b[(size_t)i * 64 + lane] = packed;
        xs[wid * 68 + lane] = packed;
    }
    __syncthreads();

    // strip GEMM: waves 0..7, wave wid handles n-tile nt=wid
    if (wid < 8) {
        int m = lane & 15, quad = lane >> 4;
        const unsigned short* xr = (const unsigned short*)xs + m * 136 + quad * 8;
        short8 afr[4];
#pragma unroll
        for (int ks = 0; ks < 4; ks++) afr[ks] = *(const short8*)(xr + ks * 32);
        float4 dv = *(const float4*)(dis + row0 + quad * 4);
        float dr[4] = {dv.x, dv.y, dv.z, dv.w};
        const short8* bp = (const short8*)Wb + (size_t)lane;
        float4v acc = {0.f, 0.f, 0.f, 0.f};
#pragma unroll
        for (int ks = 0; ks < 4; ks++)
            acc = __builtin_amdgcn_mfma_f32_16x16x32_bf16(afr[ks], bp[(wid * 4 + ks) * 64], acc, 0, 0, 0);
        int col = wid * 16 + m;
#pragma unroll
        for (int r = 0; r < 4; r++) {
            int row = row0 + quad * 4 + r;
            if (row < N) hb[(size_t)row * DD + col] = f2bf(acc[r] * dr[r]);
        }
    }
}

// ---- layer 2 fused: gather-reduce bf16 pre-scaled h2 rows + self-loop + residual + LN -> out
__global__ __launch_bounds__(256) void k_node2(const int* __restrict__ rowptr,
                                               const int* __restrict__ srcs,
                                               const unsigned* __restrict__ x1b,
                                               const unsigned* __restrict__ h2b,
                                               const float* __restrict__ dis,
                                               const float* __restrict__ b2,
                                               const float* __restrict__ g2,
                                               const float* __restrict__ beta2,
                                               float* __restrict__ out, int N) {
    int i = (blockIdx.x * blockDim.x + threadIdx.x) >> 6;
    int lane = threadIdx.x & 63;
    if (i >= N) return;
    int r0 = rowptr[i], r1 = rowptr[i + 1];
    int c = lane * 2;
    float ax = 0.f, ay = 0.f;
    int j = r0;
    for (; j + 7 < r1; j += 8) {
        float axp = 0.f, ayp = 0.f;
#pragma unroll
        for (int q = 0; q < 8; q++) {
            unsigned a = h2b[(size_t)srcs[j + q] * 64 + lane];
            axp += bflo(a); ayp += bfhi(a);
        }
        ax += axp; ay += ayp;
    }
    for (; j < r1; j++) {
        unsigned a = h2b[(size_t)srcs[j] * 64 + lane];
        ax += bflo(a); ay += bfhi(a);
    }
    float di = dis[i];
    unsigned xv = x1b[(size_t)i * 64 + lane];
    unsigned hv = h2b[(size_t)i * 64 + lane];   // already scaled by dis[i]
    float v0 = bflo(xv) + di * (ax + bflo(hv)) + b2[c];
    float v1 = bfhi(xv) + di * (ay + bfhi(hv)) + b2[c + 1];
    float sum = v0 + v1;
#pragma unroll
    for (int o = 32; o >= 1; o >>= 1) sum += __shfl_xor(sum, o, 64);
    float mu = sum * (1.f / DD);
    float d0 = v0 - mu, d1 = v1 - mu;
    float ss = d0 * d0 + d1 * d1;
#pragma unroll
    for (int o = 32; o >= 1; o >>= 1) ss += __shfl_xor(ss, o, 64);
    float r = rsqrtf(ss * (1.f / DD) + 1e-5f);
    float2 outv;
    outv.x = d0 * r * g2[c] + beta2[c];
    outv.y = d1 * r * g2[c + 1] + beta2[c + 1];
    *(float2*)(out + (size_t)i * DD + c) = outv;
}

extern "C" void kernel_launch(void* const* d_in, const int* in_sizes, int n_in,
                              void* d_out, int out_size, void* d_ws, size_t ws_size,
                              hipStream_t stream) {
    const int* node_ids = (const int*)d_in[0];
    const int* edge_index = (const int*)d_in[1];
    const float* emb   = (const float*)d_in[2];
    const float* W1    = (const float*)d_in[3];
    const float* b1    = (const float*)d_in[4];
    const float* W2    = (const float*)d_in[5];
    const float* b2    = (const float*)d_in[6];
    const float* g1    = (const float*)d_in[7];
    const float* beta1 = (const float*)d_in[8];
    const float* g2    = (const float*)d_in[9];
    const float* beta2 = (const float*)d_in[10];
    const int N = in_sizes[0];
    const int E = in_sizes[1] / 2;
    const int* srcp = edge_index;
    const int* dstp = edge_index + E;
    float* out = (float*)d_out;

    char* base = (char*)d_ws;
    size_t off = 0;
    auto carve = [&](size_t bytes) -> void* {
        void* p = base + off;
        off += (bytes + 255) & ~(size_t)255;
        return p;
    };
    int*      cnt    = (int*)carve((size_t)N * 4);
    int*      rowptr = (int*)carve((size_t)(N + 1) * 4);
    int*      cursor = (int*)carve((size_t)N * 4);
    float*    dis    = (float*)carve((size_t)(N + 16) * 4);
    int*      bsum   = (int*)carve((size_t)256 * 4);
    int*      srcs   = (int*)carve((size_t)E * 4);
    unsigned* embW1b = (unsigned*)carve((size_t)512 * 64 * 4);
    unsigned* x1b    = (unsigned*)carve((size_t)(N + 16) * 64 * 4);
    unsigned* h2b    = (unsigned*)carve((size_t)(N + 16) * 64 * 4);
    unsigned short* Wb = (unsigned short*)carve((size_t)DD * DD * 2);
    (void)ws_size; (void)n_in; (void)out_size;

    const int TB = 256;
    const int B = (N + 1023) / 1024;                  // 49
    const int zeroBlocks = (N + 1023) / 1024;         // 49 (int4 x 256 thr = 1024/blk)

    k_init<<<136 + zeroBlocks, TB, 0, stream>>>(emb, W1, W2, embW1b, Wb, cnt, N);
    k_hist<<<(E + TB - 1) / TB, TB, 0, stream>>>(dstp, cnt, E);
    k_scan1<<<B, 256, 0, stream>>>(cnt, rowptr, dis, bsum, N);
    k_scan23<<<(N + TB - 1) / TB, TB, 0, stream>>>(rowptr, cursor, bsum, B, N, E);
    k_bucket<<<(E + TB - 1) / TB, TB, 0, stream>>>(srcp, dstp, cursor, srcs, E);

    int strips = (N + 15) / 16;                       // 3125
    k_node1g<<<strips, 1024, 0, stream>>>(rowptr, srcs, node_ids, emb, embW1b, dis,
                                          b1, g1, beta1, x1b, Wb,
                                          (unsigned short*)h2b, N);
    int nodeBlocks = (N * 64 + TB - 1) / TB;
    k_node2<<<nodeBlocks, TB, 0, stream>>>(rowptr, srcs, x1b, h2b, dis,
                                           b2, g2, beta2, out, N);
}